// Round 5
// baseline (73.758 us; speedup 1.0000x reference)
//
#include <hip/hip_runtime.h>
#include <math.h>

#define BATCH 32
#define HW 16384
#define WIDTH 128
#define NLINES 1000
#define NCAND 4096
#define SLOTS_PER_BLOCK 64   // hard bound: max local maxima in a 2x128 tile

// Flat output offsets (float elements), reference return order:
// lcmap (32,128,128), lcoff (32,2,128,128), lleng (32,128,128),
// angle (32,128,128), lines (32,1000,2,2), score (32,1000)
#define OFF_LCMAP 0
#define OFF_LCOFF (BATCH * HW)
#define OFF_LLENG (OFF_LCOFF + 2 * BATCH * HW)
#define OFF_ANGLE (OFF_LLENG + BATCH * HW)
#define OFF_LINES (OFF_ANGLE + BATCH * HW)
#define OFF_SCORE (OFF_LINES + BATCH * NLINES * 4)

// Workspace: 32 batches x 4096 u64 keys (no counters, no atomics).
#define WS_NEEDED ((size_t)BATCH * NCAND * 8)

#define PI_F 3.14159265358979323846f

__device__ __forceinline__ float sigmoidf_(float x) {
    return 1.0f / (1.0f + expf(-x));
}

// Exactly the reference softmax([x0,x1])[1] op sequence (do NOT reformulate
// as sigmoid(x1-x0): ulp-level changes can flip top-k orderings).
__device__ __forceinline__ float softmax1(float x0, float x1) {
    float m = fmaxf(x0, x1);
    float e0 = expf(x0 - m);
    float e1 = expf(x1 - m);
    return e1 / (e0 + e1);
}

__device__ __forceinline__ unsigned long long pack_key(float v, unsigned p) {
    // v > 0 -> float-bit order == value order; inverted index replicates
    // stable lax.top_k tie-breaking (lower index first). Never 0 for a real
    // candidate (low word = ~p != 0), so 0 marks an empty slot.
    return ((unsigned long long)__float_as_uint(v) << 32)
         | (unsigned long long)(0xFFFFFFFFu - p);
}

// K1: elementwise transforms + fused local-max collection, ATOMIC-FREE.
// Block = 256 threads = 2 rows of one batch; fixed 64-slot output region per
// block, slot assignment via block-local LDS prefix; unused slots zeroed.
__global__ __launch_bounds__(256) void prep_collect_kernel(
        const float* __restrict__ in, float* __restrict__ out,
        unsigned long long* __restrict__ wskeys) {
    __shared__ int wcnt_s[4];
    __shared__ int wpre_s[4];
    __shared__ int tot_s;

    int tid = blockIdx.x * 256 + threadIdx.x;
    int b = tid >> 14;              // HW = 16384
    int p = tid & (HW - 1);
    const float* __restrict__ ib = in + (size_t)b * 6 * HW;

    float x0 = ib[p];
    float x1 = ib[HW + p];
    float x2 = ib[2 * HW + p];
    float x3 = ib[3 * HW + p];
    float x4 = ib[4 * HW + p];
    float x5 = ib[5 * HW + p];

    float v = softmax1(x0, x1);
    out[OFF_LCMAP + tid] = v;
    out[OFF_LCOFF + b * 2 * HW + p]      = sigmoidf_(x2) - 0.5f;
    out[OFF_LCOFF + b * 2 * HW + HW + p] = sigmoidf_(x3) - 0.5f;
    out[OFF_LLENG + tid] = sigmoidf_(x4);
    out[OFF_ANGLE + tid] = sigmoidf_(x5);

    // 3x3 local-max test vs in-bounds neighbors (== h == maxpool3x3(h)).
    // Neighbor lcmap recomputed from input: bit-identical to stored values.
    int y = p >> 7, x = p & (WIDTH - 1);
    float m = -INFINITY;
    #pragma unroll
    for (int dy = -1; dy <= 1; ++dy) {
        #pragma unroll
        for (int dx = -1; dx <= 1; ++dx) {
            if (dy == 0 && dx == 0) continue;
            int yy = y + dy, xx = x + dx;
            int yc = min(max(yy, 0), WIDTH - 1);
            int xc = min(max(xx, 0), WIDTH - 1);
            int np = yc * WIDTH + xc;
            float nv = softmax1(ib[np], ib[HW + np]);
            bool inb = ((unsigned)yy < (unsigned)WIDTH) & ((unsigned)xx < (unsigned)WIDTH);
            m = fmaxf(m, inb ? nv : -INFINITY);
        }
    }
    bool keep = (v >= m);

    // Block-local compaction: wave popcounts -> exclusive prefix (thread 0).
    unsigned long long mask = __ballot(keep);
    int lane = threadIdx.x & 63;
    int w = threadIdx.x >> 6;
    if (lane == 0) wcnt_s[w] = __popcll(mask);
    __syncthreads();
    if (threadIdx.x == 0) {
        int a0 = wcnt_s[0], a1 = wcnt_s[1], a2 = wcnt_s[2], a3 = wcnt_s[3];
        wpre_s[0] = 0; wpre_s[1] = a0; wpre_s[2] = a0 + a1; wpre_s[3] = a0 + a1 + a2;
        tot_s = a0 + a1 + a2 + a3;
    }
    __syncthreads();

    unsigned long long* __restrict__ gk =
        wskeys + (size_t)b * NCAND + (size_t)(blockIdx.x & 63) * SLOTS_PER_BLOCK;
    if (keep) {
        int pos = wpre_s[w] + __popcll(mask & ((1ULL << lane) - 1ULL));
        if (pos < SLOTS_PER_BLOCK)           // unreachable for continuous data
            gk[pos] = pack_key(v, (unsigned)p);
    }
    int tot = tot_s < SLOTS_PER_BLOCK ? tot_s : SLOTS_PER_BLOCK;
    if (threadIdx.x < SLOTS_PER_BLOCK && threadIdx.x >= tot)
        gk[threadIdx.x] = 0ULL;              // zero-fill empty slots
}

// Serial keep test on stored lcmap (cold fallback path only).
__device__ bool keep_at(const float* __restrict__ L, int p) {
    int y = p >> 7, x = p & (WIDTH - 1);
    float v = L[p];
    for (int dy = -1; dy <= 1; ++dy) {
        int yy = y + dy;
        if (yy < 0 || yy >= WIDTH) continue;
        for (int dx = -1; dx <= 1; ++dx) {
            if (dy == 0 && dx == 0) continue;
            int xx = x + dx;
            if (xx < 0 || xx >= WIDTH) continue;
            if (L[yy * WIDTH + xx] > v) return false;
        }
    }
    return true;
}

// K2: per-batch fused rank+lines: full 4096-key in-LDS bitonic sort
// (descending; zeros sink to the tail), then slot k == rank k. Emits line
// endpoints + raw scores for ranks < 1000. Integrated never-triggering
// fallback (cnt < 1000 -> top_k zero-padding at lowest non-kept indices).
__global__ __launch_bounds__(1024) void rank_lines_kernel(
        float* __restrict__ out, const unsigned long long* __restrict__ wskeys) {
    __shared__ unsigned long long sk[NCAND];   // 32 KB
    __shared__ int cnt_s;
    const int b = blockIdx.x;
    const unsigned long long* gk = wskeys + (size_t)b * NCAND;
    for (int i = threadIdx.x; i < NCAND; i += 1024) sk[i] = gk[i];
    __syncthreads();

    // Bitonic sort over 4096, 2 disjoint compare-swap pairs per thread/phase.
    for (int size = 2; size <= NCAND; size <<= 1) {
        for (int stride = size >> 1; stride > 0; stride >>= 1) {
            #pragma unroll
            for (int pp = 0; pp < 2; ++pp) {
                int t = threadIdx.x + (pp << 10);
                int i = ((t & ~(stride - 1)) << 1) | (t & (stride - 1));
                int j = i | stride;
                bool asc = (i & size) != 0;
                unsigned long long a = sk[i], cc = sk[j];
                if ((a < cc) != asc) { sk[i] = cc; sk[j] = a; }
            }
            __syncthreads();
        }
    }

    // cnt = index of first zero (keys sorted descending, zeros at tail).
    if (threadIdx.x == 0) {
        int lo = 0, hi = NCAND;
        while (lo < hi) {
            int mid = (lo + hi) >> 1;
            if (sk[mid] != 0ULL) lo = mid + 1; else hi = mid;
        }
        cnt_s = lo;
    }
    __syncthreads();
    const int cnt = cnt_s;
    const int nvalid = cnt < NLINES ? cnt : NLINES;

    const float* off0 = out + OFF_LCOFF + b * 2 * HW;
    const float* off1 = off0 + HW;
    const float* leng = out + OFF_LLENG + b * HW;
    const float* ang  = out + OFF_ANGLE + b * HW;

    const int k = threadIdx.x;
    if (k < nvalid) {
        unsigned long long e = sk[k];
        unsigned p = 0xFFFFFFFFu - (unsigned)(e & 0xFFFFFFFFull);
        float score = __uint_as_float((unsigned)(e >> 32));
        int yi = (int)(p >> 7), xi = (int)(p & (WIDTH - 1));
        float yc = (float)yi + off0[p] + 0.5f;
        float xc = (float)xi + off1[p] + 0.5f;
        float hl = leng[p] * 64.0f;              // RESOLUTION/2
        float th = ang[p] * PI_F;
        float dy = hl * sinf(th);
        float dx = hl * cosf(th);
        float4 ln = make_float4(yc - dy, xc - dx, yc + dy, xc + dx);
        *(float4*)(out + OFF_LINES + (size_t)(b * NLINES + k) * 4) = ln;
        out[OFF_SCORE + b * NLINES + k] = score;
    }

    // Fallback (never triggers for this data): pad ranks [cnt, 1000) with the
    // lowest non-kept flat indices, score 0.
    if (cnt < NLINES && threadIdx.x == 0) {
        const float* L = out + OFF_LCMAP + b * HW;
        int rank = cnt;
        for (int p = 0; p < HW && rank < NLINES; ++p) {
            if (keep_at(L, p)) continue;
            int yi = p >> 7, xi = p & (WIDTH - 1);
            float yc = (float)yi + off0[p] + 0.5f;
            float xc = (float)xi + off1[p] + 0.5f;
            float hl = leng[p] * 64.0f;
            float th = ang[p] * PI_F;
            float dy = hl * sinf(th);
            float dx = hl * cosf(th);
            float* lo = out + OFF_LINES + (size_t)(b * NLINES + rank) * 4;
            lo[0] = yc - dy; lo[1] = xc - dx; lo[2] = yc + dy; lo[3] = xc + dx;
            out[OFF_SCORE + b * NLINES + rank] = 0.0f;
            ++rank;
        }
    }
}

// K3: structure NMS. Grid (16 k-tiles, 32 batches); block = 64 k x 4 i-splits.
// __f*_rn intrinsics forbid fma contraction so dist matches reference rounding.
__global__ __launch_bounds__(256) void nms_kernel(float* __restrict__ out) {
    __shared__ float4 lsv[NLINES];               // 16 KB
    __shared__ unsigned char flags[64][4];
    const int tile = blockIdx.x, b = blockIdx.y;
    const float4* lg = (const float4*)(out + OFF_LINES + (size_t)b * NLINES * 4);
    for (int i = threadIdx.x; i < NLINES; i += 256) lsv[i] = lg[i];
    __syncthreads();

    const int s  = threadIdx.x >> 6;             // i-range split 0..3
    const int kl = threadIdx.x & 63;
    const int k  = tile * 64 + kl;
    float4 P = lsv[k < NLINES ? k : 0];

    int istart = s * 250;
    int iend = min(250 * (s + 1), min(k, NLINES));
    bool sup = false;
    for (int i = istart; i < iend; ++i) {
        float4 Q = lsv[i];
        float a1 = __fadd_rn(__fmul_rn(Q.x - P.x, Q.x - P.x),
                             __fmul_rn(Q.y - P.y, Q.y - P.y));
        float a2 = __fadd_rn(__fmul_rn(Q.z - P.z, Q.z - P.z),
                             __fmul_rn(Q.w - P.w, Q.w - P.w));
        float d1 = __fadd_rn(a1, a2);
        float b1 = __fadd_rn(__fmul_rn(Q.x - P.z, Q.x - P.z),
                             __fmul_rn(Q.y - P.w, Q.y - P.w));
        float b2 = __fadd_rn(__fmul_rn(Q.z - P.x, Q.z - P.x),
                             __fmul_rn(Q.w - P.y, Q.w - P.y));
        float d2 = __fadd_rn(b1, b2);
        sup |= (fminf(d1, d2) <= 2.0f);
    }
    flags[kl][s] = (unsigned char)sup;
    __syncthreads();

    if (s == 0 && k < NLINES) {
        bool any = flags[kl][0] | flags[kl][1] | flags[kl][2] | flags[kl][3];
        float sc = out[OFF_SCORE + b * NLINES + k];
        out[OFF_SCORE + b * NLINES + k] = any ? 0.0f : sc;
    }
}

extern "C" void kernel_launch(void* const* d_in, const int* in_sizes, int n_in,
                              void* d_out, int out_size, void* d_ws, size_t ws_size,
                              hipStream_t stream) {
    const float* in = (const float*)d_in[0];
    float* out = (float*)d_out;
    (void)in_sizes; (void)n_in; (void)out_size;

    if (d_ws == nullptr || ws_size < WS_NEEDED) return;  // ws >= 1MB confirmed
    unsigned long long* wskeys = (unsigned long long*)d_ws;

    prep_collect_kernel<<<(BATCH * HW) / 256, 256, 0, stream>>>(in, out, wskeys);
    rank_lines_kernel<<<BATCH, 1024, 0, stream>>>(out, wskeys);
    nms_kernel<<<dim3(16, BATCH), 256, 0, stream>>>(out);
}

// Round 6
// 57.155 us; speedup vs baseline: 1.2905x; 1.2905x over previous
//
#include <hip/hip_runtime.h>
#include <math.h>

#define BATCH 32
#define HW 16384
#define WIDTH 128
#define NLINES 1000
#define NCAND 4096
#define CHUNK 1024
#define NCHUNK 4
#define SLOTS_PER_BLOCK 64   // hard bound: max local maxima in a 2x128 tile

// Flat output offsets (float elements), reference return order:
// lcmap (32,128,128), lcoff (32,2,128,128), lleng (32,128,128),
// angle (32,128,128), lines (32,1000,2,2), score (32,1000)
#define OFF_LCMAP 0
#define OFF_LCOFF (BATCH * HW)
#define OFF_LLENG (OFF_LCOFF + 2 * BATCH * HW)
#define OFF_ANGLE (OFF_LLENG + BATCH * HW)
#define OFF_LINES (OFF_ANGLE + BATCH * HW)
#define OFF_SCORE (OFF_LINES + BATCH * NLINES * 4)

// Workspace: 32 batches x 4096 u64 keys (no counters, no atomics).
#define WS_NEEDED ((size_t)BATCH * NCAND * 8)

#define PI_F 3.14159265358979323846f

// NMS decomposition: 64 k-tiles of 16, 16 i-splits of 63 (covers 1008 >= 1000)
#define NMS_KTILE 16
#define NMS_NSPLIT 16
#define NMS_SPLIT 63

__device__ __forceinline__ float sigmoidf_(float x) {
    return 1.0f / (1.0f + expf(-x));
}

// Exactly the reference softmax([x0,x1])[1] op sequence (do NOT reformulate
// as sigmoid(x1-x0): ulp-level changes can flip top-k orderings).
__device__ __forceinline__ float softmax1(float x0, float x1) {
    float m = fmaxf(x0, x1);
    float e0 = expf(x0 - m);
    float e1 = expf(x1 - m);
    return e1 / (e0 + e1);
}

__device__ __forceinline__ unsigned long long pack_key(float v, unsigned p) {
    // v > 0 -> float-bit order == value order; inverted index replicates
    // stable lax.top_k tie-breaking (lower index first). Never 0 for a real
    // candidate (low word = ~p != 0), so 0 marks an empty slot.
    return ((unsigned long long)__float_as_uint(v) << 32)
         | (unsigned long long)(0xFFFFFFFFu - p);
}

// K1: elementwise transforms + fused local-max collection, ATOMIC-FREE.
// Block = 256 threads = 2 rows of one batch; fixed 64-slot output region per
// block, slot assignment via block-local LDS prefix; unused slots zeroed.
__global__ __launch_bounds__(256) void prep_collect_kernel(
        const float* __restrict__ in, float* __restrict__ out,
        unsigned long long* __restrict__ wskeys) {
    __shared__ int wcnt_s[4];
    __shared__ int wpre_s[4];
    __shared__ int tot_s;

    int tid = blockIdx.x * 256 + threadIdx.x;
    int b = tid >> 14;              // HW = 16384
    int p = tid & (HW - 1);
    const float* __restrict__ ib = in + (size_t)b * 6 * HW;

    float x0 = ib[p];
    float x1 = ib[HW + p];
    float x2 = ib[2 * HW + p];
    float x3 = ib[3 * HW + p];
    float x4 = ib[4 * HW + p];
    float x5 = ib[5 * HW + p];

    float v = softmax1(x0, x1);
    out[OFF_LCMAP + tid] = v;
    out[OFF_LCOFF + b * 2 * HW + p]      = sigmoidf_(x2) - 0.5f;
    out[OFF_LCOFF + b * 2 * HW + HW + p] = sigmoidf_(x3) - 0.5f;
    out[OFF_LLENG + tid] = sigmoidf_(x4);
    out[OFF_ANGLE + tid] = sigmoidf_(x5);

    // 3x3 local-max test vs in-bounds neighbors (== h == maxpool3x3(h)).
    // Neighbor lcmap recomputed from input: bit-identical to stored values.
    int y = p >> 7, x = p & (WIDTH - 1);
    float m = -INFINITY;
    #pragma unroll
    for (int dy = -1; dy <= 1; ++dy) {
        #pragma unroll
        for (int dx = -1; dx <= 1; ++dx) {
            if (dy == 0 && dx == 0) continue;
            int yy = y + dy, xx = x + dx;
            int yc = min(max(yy, 0), WIDTH - 1);
            int xc = min(max(xx, 0), WIDTH - 1);
            int np = yc * WIDTH + xc;
            float nv = softmax1(ib[np], ib[HW + np]);
            bool inb = ((unsigned)yy < (unsigned)WIDTH) & ((unsigned)xx < (unsigned)WIDTH);
            m = fmaxf(m, inb ? nv : -INFINITY);
        }
    }
    bool keep = (v >= m);

    // Block-local compaction: wave popcounts -> exclusive prefix (thread 0).
    unsigned long long mask = __ballot(keep);
    int lane = threadIdx.x & 63;
    int w = threadIdx.x >> 6;
    if (lane == 0) wcnt_s[w] = __popcll(mask);
    __syncthreads();
    if (threadIdx.x == 0) {
        int a0 = wcnt_s[0], a1 = wcnt_s[1], a2 = wcnt_s[2], a3 = wcnt_s[3];
        wpre_s[0] = 0; wpre_s[1] = a0; wpre_s[2] = a0 + a1; wpre_s[3] = a0 + a1 + a2;
        tot_s = a0 + a1 + a2 + a3;
    }
    __syncthreads();

    unsigned long long* __restrict__ gk =
        wskeys + (size_t)b * NCAND + (size_t)(blockIdx.x & 63) * SLOTS_PER_BLOCK;
    if (keep) {
        int pos = wpre_s[w] + __popcll(mask & ((1ULL << lane) - 1ULL));
        if (pos < SLOTS_PER_BLOCK)           // unreachable for continuous data
            gk[pos] = pack_key(v, (unsigned)p);
    }
    int tot = tot_s < SLOTS_PER_BLOCK ? tot_s : SLOTS_PER_BLOCK;
    if (threadIdx.x < SLOTS_PER_BLOCK && threadIdx.x >= tot)
        gk[threadIdx.x] = 0ULL;              // zero-fill empty slots
}

// K2: per-(batch,chunk) bitonic sort of 1024 keys, descending.
__global__ __launch_bounds__(512) void sort_chunks_kernel(
        unsigned long long* __restrict__ wskeys) {
    __shared__ unsigned long long sk[CHUNK];
    const int c = blockIdx.x, b = blockIdx.y;
    const int base = c * CHUNK;
    unsigned long long* gk = wskeys + (size_t)b * NCAND;

    for (int i = threadIdx.x; i < CHUNK; i += 512) sk[i] = gk[base + i];
    __syncthreads();

    for (int size = 2; size <= CHUNK; size <<= 1) {
        for (int stride = size >> 1; stride > 0; stride >>= 1) {
            int t = threadIdx.x;
            int i = ((t & ~(stride - 1)) << 1) | (t & (stride - 1));
            int j = i | stride;
            bool asc = (i & size) != 0;
            unsigned long long a = sk[i], cc = sk[j];
            if ((a < cc) != asc) { sk[i] = cc; sk[j] = a; }
            __syncthreads();
        }
    }
    for (int i = threadIdx.x; i < CHUNK; i += 512) gk[base + i] = sk[i];
}

// Serial keep test on stored lcmap (cold fallback path only).
__device__ bool keep_at(const float* __restrict__ L, int p) {
    int y = p >> 7, x = p & (WIDTH - 1);
    float v = L[p];
    for (int dy = -1; dy <= 1; ++dy) {
        int yy = y + dy;
        if (yy < 0 || yy >= WIDTH) continue;
        for (int dx = -1; dx <= 1; ++dx) {
            if (dy == 0 && dx == 0) continue;
            int xx = x + dx;
            if (xx < 0 || xx >= WIDTH) continue;
            if (L[yy * WIDTH + xx] > v) return false;
        }
    }
    return true;
}

// K3: merge 4 sorted chunks by exact rank (binary search; nonzero keys are
// unique), compute line endpoints + raw scores for ranks < 1000. Includes
// the never-triggering cnt<1000 zero-pad fallback (folded former fb_fill).
__global__ __launch_bounds__(1024) void merge_lines_kernel(
        float* __restrict__ out, const unsigned long long* __restrict__ wskeys) {
    __shared__ unsigned long long sk[NCAND];   // 32 KB
    __shared__ int wsum[16];
    __shared__ int cnt_s;
    const int b = blockIdx.x;
    const unsigned long long* gk = wskeys + (size_t)b * NCAND;
    for (int i = threadIdx.x; i < NCAND; i += 1024) sk[i] = gk[i];
    __syncthreads();

    // Candidate count = number of nonzero keys (wave + LDS reduction).
    int local = 0;
    for (int i = threadIdx.x; i < NCAND; i += 1024) local += (sk[i] != 0ULL);
    for (int off = 32; off; off >>= 1) local += __shfl_down(local, off);
    if ((threadIdx.x & 63) == 0) wsum[threadIdx.x >> 6] = local;
    __syncthreads();
    if (threadIdx.x == 0) {
        int s = 0;
        #pragma unroll
        for (int i = 0; i < 16; ++i) s += wsum[i];
        cnt_s = s;
    }
    __syncthreads();
    const int cnt = cnt_s;

    const float* off0 = out + OFF_LCOFF + b * 2 * HW;
    const float* off1 = off0 + HW;
    const float* leng = out + OFF_LLENG + b * HW;
    const float* ang  = out + OFF_ANGLE + b * HW;

    for (int mslot = threadIdx.x; mslot < NCAND; mslot += 1024) {
        unsigned long long e = sk[mslot];
        if (e == 0ULL) continue;                 // empty slot
        int c = mslot >> 10;
        int rank = mslot & (CHUNK - 1);          // local rank in own chunk
        #pragma unroll
        for (int c2 = 0; c2 < NCHUNK; ++c2) {
            if (c2 == c) continue;
            const unsigned long long* A = sk + c2 * CHUNK;
            int lo = 0, hi = CHUNK;
            while (lo < hi) {
                int mid = (lo + hi) >> 1;
                if (A[mid] > e) lo = mid + 1; else hi = mid;
            }
            rank += lo;                          // count of keys > e in c2
        }
        if (rank < NLINES) {
            unsigned p = 0xFFFFFFFFu - (unsigned)(e & 0xFFFFFFFFull);
            float score = __uint_as_float((unsigned)(e >> 32));
            int yi = (int)(p >> 7), xi = (int)(p & (WIDTH - 1));
            float yc = (float)yi + off0[p] + 0.5f;
            float xc = (float)xi + off1[p] + 0.5f;
            float hl = leng[p] * 64.0f;          // RESOLUTION/2
            float th = ang[p] * PI_F;
            float dy = hl * sinf(th);
            float dx = hl * cosf(th);
            float4 ln = make_float4(yc - dy, xc - dx, yc + dy, xc + dx);
            *(float4*)(out + OFF_LINES + (size_t)(b * NLINES + rank) * 4) = ln;
            out[OFF_SCORE + b * NLINES + rank] = score;
        }
    }

    // Fallback (never triggers for this data): pad ranks [cnt, 1000) with the
    // lowest non-kept flat indices, score 0. Disjoint ranks from the loop
    // above -> no barrier needed.
    if (cnt < NLINES && threadIdx.x == 0) {
        const float* L = out + OFF_LCMAP + b * HW;
        int rank = cnt;
        for (int p = 0; p < HW && rank < NLINES; ++p) {
            if (keep_at(L, p)) continue;
            int yi = p >> 7, xi = p & (WIDTH - 1);
            float yc = (float)yi + off0[p] + 0.5f;
            float xc = (float)xi + off1[p] + 0.5f;
            float hl = leng[p] * 64.0f;
            float th = ang[p] * PI_F;
            float dy = hl * sinf(th);
            float dx = hl * cosf(th);
            float* lo = out + OFF_LINES + (size_t)(b * NLINES + rank) * 4;
            lo[0] = yc - dy; lo[1] = xc - dx; lo[2] = yc + dy; lo[3] = xc + dx;
            out[OFF_SCORE + b * NLINES + rank] = 0.0f;
            ++rank;
        }
    }
}

// K4: structure NMS. Grid (64 k-tiles, 32 batches), block 256 =
// 16 k x 16 i-splits of 63 -> max 63 iters/lane, uniform within a wave,
// 2048 small blocks load-balance across CUs.
// __f*_rn intrinsics forbid fma contraction so dist matches reference rounding.
__global__ __launch_bounds__(256) void nms_kernel(float* __restrict__ out) {
    __shared__ float4 lsv[NLINES];               // 16 KB
    __shared__ unsigned char flags[NMS_KTILE][NMS_NSPLIT];
    const int tile = blockIdx.x, b = blockIdx.y;
    const float4* lg = (const float4*)(out + OFF_LINES + (size_t)b * NLINES * 4);
    for (int i = threadIdx.x; i < NLINES; i += 256) lsv[i] = lg[i];
    __syncthreads();

    const int kl = threadIdx.x & (NMS_KTILE - 1);
    const int s  = threadIdx.x >> 4;             // i-range split 0..15
    const int k  = tile * NMS_KTILE + kl;
    float4 P = lsv[k < NLINES ? k : 0];

    int istart = s * NMS_SPLIT;
    int iend = min(NMS_SPLIT * (s + 1), min(k, NLINES));
    bool sup = false;
    for (int i = istart; i < iend; ++i) {
        float4 Q = lsv[i];
        float a1 = __fadd_rn(__fmul_rn(Q.x - P.x, Q.x - P.x),
                             __fmul_rn(Q.y - P.y, Q.y - P.y));
        float a2 = __fadd_rn(__fmul_rn(Q.z - P.z, Q.z - P.z),
                             __fmul_rn(Q.w - P.w, Q.w - P.w));
        float d1 = __fadd_rn(a1, a2);
        float b1 = __fadd_rn(__fmul_rn(Q.x - P.z, Q.x - P.z),
                             __fmul_rn(Q.y - P.w, Q.y - P.w));
        float b2 = __fadd_rn(__fmul_rn(Q.z - P.x, Q.z - P.x),
                             __fmul_rn(Q.w - P.y, Q.w - P.y));
        float d2 = __fadd_rn(b1, b2);
        sup |= (fminf(d1, d2) <= 2.0f);
    }
    flags[kl][s] = (unsigned char)sup;
    __syncthreads();

    if (s == 0 && k < NLINES) {
        int any = 0;
        #pragma unroll
        for (int i = 0; i < NMS_NSPLIT; ++i) any |= flags[kl][i];
        float sc = out[OFF_SCORE + b * NLINES + k];
        out[OFF_SCORE + b * NLINES + k] = any ? 0.0f : sc;
    }
}

extern "C" void kernel_launch(void* const* d_in, const int* in_sizes, int n_in,
                              void* d_out, int out_size, void* d_ws, size_t ws_size,
                              hipStream_t stream) {
    const float* in = (const float*)d_in[0];
    float* out = (float*)d_out;
    (void)in_sizes; (void)n_in; (void)out_size;

    if (d_ws == nullptr || ws_size < WS_NEEDED) return;  // ws = 256 MiB confirmed
    unsigned long long* wskeys = (unsigned long long*)d_ws;

    prep_collect_kernel<<<(BATCH * HW) / 256, 256, 0, stream>>>(in, out, wskeys);
    sort_chunks_kernel<<<dim3(NCHUNK, BATCH), 512, 0, stream>>>(wskeys);
    merge_lines_kernel<<<BATCH, 1024, 0, stream>>>(out, wskeys);
    nms_kernel<<<dim3(64, BATCH), 256, 0, stream>>>(out);
}

// Round 7
// 50.998 us; speedup vs baseline: 1.4463x; 1.1207x over previous
//
#include <hip/hip_runtime.h>
#include <math.h>

#define BATCH 32
#define HW 16384
#define WIDTH 128
#define NLINES 1000
#define NCAND 4096
#define CHUNK 1024
#define NCHUNK 4
#define SLOTS_PER_BLOCK 64   // hard bound: max king-graph independent set in 2x128

// Flat output offsets (float elements), reference return order:
// lcmap (32,128,128), lcoff (32,2,128,128), lleng (32,128,128),
// angle (32,128,128), lines (32,1000,2,2), score (32,1000)
#define OFF_LCMAP 0
#define OFF_LCOFF (BATCH * HW)
#define OFF_LLENG (OFF_LCOFF + 2 * BATCH * HW)
#define OFF_ANGLE (OFF_LLENG + BATCH * HW)
#define OFF_LINES (OFF_ANGLE + BATCH * HW)
#define OFF_SCORE (OFF_LINES + BATCH * NLINES * 4)

// Workspace: 32 batches x 4096 u64 keys (no counters, no atomics).
#define WS_NEEDED ((size_t)BATCH * NCAND * 8)

#define PI_F 3.14159265358979323846f

// NMS decomposition: 64 k-tiles of 16, 16 i-splits of 63 (covers 1008 >= 1000)
#define NMS_KTILE 16
#define NMS_NSPLIT 16
#define NMS_SPLIT 63

__device__ __forceinline__ float sigmoidf_(float x) {
    return 1.0f / (1.0f + expf(-x));
}

// Exactly the reference softmax([x0,x1])[1] op sequence (do NOT reformulate
// as sigmoid(x1-x0): ulp-level changes can flip top-k orderings).
__device__ __forceinline__ float softmax1(float x0, float x1) {
    float m = fmaxf(x0, x1);
    float e0 = expf(x0 - m);
    float e1 = expf(x1 - m);
    return e1 / (e0 + e1);
}

__device__ __forceinline__ unsigned long long pack_key(float v, unsigned p) {
    // v > 0 -> float-bit order == value order; inverted index replicates
    // stable lax.top_k tie-breaking (lower index first). Never 0 for a real
    // candidate (low word = ~p != 0), so 0 marks an empty slot.
    return ((unsigned long long)__float_as_uint(v) << 32)
         | (unsigned long long)(0xFFFFFFFFu - p);
}

// K1: elementwise transforms + fused local-max collection, ATOMIC-FREE.
// Block = 256 threads = 2 rows of one batch. Softmax computed ONCE per pixel
// into an LDS tile with 1-row halo (2 softmax/thread instead of 9); keep-test
// reads LDS. Fixed 64-slot output region per block via block-local prefix.
__global__ __launch_bounds__(256) void prep_collect_kernel(
        const float* __restrict__ in, float* __restrict__ out,
        unsigned long long* __restrict__ wskeys) {
    __shared__ float sm[4][WIDTH];   // rows y0-1, y0, y0+1, y0+2 (clamped)
    __shared__ int wcnt_s[4];
    __shared__ int wpre_s[4];
    __shared__ int tot_s;

    const int blk = blockIdx.x;
    const int b = blk >> 6;          // batch
    const int rp = blk & 63;         // row-pair within batch
    const int y0 = rp * 2;
    const int r = threadIdx.x >> 7;  // 0,1: which of the 2 rows
    const int c = threadIdx.x & (WIDTH - 1);
    const int y = y0 + r;
    const int p = y * WIDTH + c;
    const float* __restrict__ ib = in + (size_t)b * 6 * HW;

    float x0 = ib[p];
    float x1 = ib[HW + p];
    float x2 = ib[2 * HW + p];
    float x3 = ib[3 * HW + p];
    float x4 = ib[4 * HW + p];
    float x5 = ib[5 * HW + p];

    float v = softmax1(x0, x1);
    sm[1 + r][c] = v;
    // Halo: r==0 threads fill row y0-1 (slot 0), r==1 fill y0+2 (slot 3).
    {
        int hy = (r == 0) ? (y0 - 1) : (y0 + 2);
        int hyc = min(max(hy, 0), WIDTH - 1);
        int hp = hyc * WIDTH + c;
        sm[r == 0 ? 0 : 3][c] = softmax1(ib[hp], ib[HW + hp]);
    }

    out[OFF_LCMAP + b * HW + p] = v;
    out[OFF_LCOFF + b * 2 * HW + p]      = sigmoidf_(x2) - 0.5f;
    out[OFF_LCOFF + b * 2 * HW + HW + p] = sigmoidf_(x3) - 0.5f;
    out[OFF_LLENG + b * HW + p] = sigmoidf_(x4);
    out[OFF_ANGLE + b * HW + p] = sigmoidf_(x5);
    __syncthreads();

    // 3x3 local-max vs in-bounds neighbors, all values from LDS.
    const int ly = 1 + r;
    float m = -INFINITY;
    #pragma unroll
    for (int dy = -1; dy <= 1; ++dy) {
        #pragma unroll
        for (int dx = -1; dx <= 1; ++dx) {
            if (dy == 0 && dx == 0) continue;
            int yy = y + dy, xx = c + dx;
            int xc = min(max(xx, 0), WIDTH - 1);
            float nv = sm[ly + dy][xc];
            bool inb = ((unsigned)yy < (unsigned)WIDTH) & ((unsigned)xx < (unsigned)WIDTH);
            m = fmaxf(m, inb ? nv : -INFINITY);
        }
    }
    bool keep = (v >= m);

    // Block-local compaction: wave popcounts -> exclusive prefix (thread 0).
    unsigned long long mask = __ballot(keep);
    int lane = threadIdx.x & 63;
    int w = threadIdx.x >> 6;
    if (lane == 0) wcnt_s[w] = __popcll(mask);
    __syncthreads();
    if (threadIdx.x == 0) {
        int a0 = wcnt_s[0], a1 = wcnt_s[1], a2 = wcnt_s[2], a3 = wcnt_s[3];
        wpre_s[0] = 0; wpre_s[1] = a0; wpre_s[2] = a0 + a1; wpre_s[3] = a0 + a1 + a2;
        tot_s = a0 + a1 + a2 + a3;
    }
    __syncthreads();

    unsigned long long* __restrict__ gk =
        wskeys + (size_t)b * NCAND + (size_t)rp * SLOTS_PER_BLOCK;
    if (keep) {
        int pos = wpre_s[w] + __popcll(mask & ((1ULL << lane) - 1ULL));
        if (pos < SLOTS_PER_BLOCK)           // unreachable for continuous data
            gk[pos] = pack_key(v, (unsigned)p);
    }
    int tot = tot_s < SLOTS_PER_BLOCK ? tot_s : SLOTS_PER_BLOCK;
    if (threadIdx.x < SLOTS_PER_BLOCK && threadIdx.x >= tot)
        gk[threadIdx.x] = 0ULL;              // zero-fill empty slots
}

// K2: per-(batch,chunk) bitonic sort of 1024 keys, descending.
__global__ __launch_bounds__(512) void sort_chunks_kernel(
        unsigned long long* __restrict__ wskeys) {
    __shared__ unsigned long long sk[CHUNK];
    const int c = blockIdx.x, b = blockIdx.y;
    const int base = c * CHUNK;
    unsigned long long* gk = wskeys + (size_t)b * NCAND;

    for (int i = threadIdx.x; i < CHUNK; i += 512) sk[i] = gk[base + i];
    __syncthreads();

    for (int size = 2; size <= CHUNK; size <<= 1) {
        for (int stride = size >> 1; stride > 0; stride >>= 1) {
            int t = threadIdx.x;
            int i = ((t & ~(stride - 1)) << 1) | (t & (stride - 1));
            int j = i | stride;
            bool asc = (i & size) != 0;
            unsigned long long a = sk[i], cc = sk[j];
            if ((a < cc) != asc) { sk[i] = cc; sk[j] = a; }
            __syncthreads();
        }
    }
    for (int i = threadIdx.x; i < CHUNK; i += 512) gk[base + i] = sk[i];
}

// Serial keep test on stored lcmap (cold fallback path only).
__device__ bool keep_at(const float* __restrict__ L, int p) {
    int y = p >> 7, x = p & (WIDTH - 1);
    float v = L[p];
    for (int dy = -1; dy <= 1; ++dy) {
        int yy = y + dy;
        if (yy < 0 || yy >= WIDTH) continue;
        for (int dx = -1; dx <= 1; ++dx) {
            if (dy == 0 && dx == 0) continue;
            int xx = x + dx;
            if (xx < 0 || xx >= WIDTH) continue;
            if (L[yy * WIDTH + xx] > v) return false;
        }
    }
    return true;
}

// K3: merge 4 sorted chunks by exact rank. Grid (4 chunks, 32 batches) =
// 128 blocks x 256 threads; each block loads all 4 chunks into LDS (L2-hit
// redundancy) and ranks its own chunk's 1024 keys via 3 binary searches.
// Chunk-0 block also handles the never-triggering cnt<1000 zero-pad fallback.
__global__ __launch_bounds__(256) void merge_lines_kernel(
        float* __restrict__ out, const unsigned long long* __restrict__ wskeys) {
    __shared__ unsigned long long sk[NCAND];   // 32 KB
    __shared__ int wsum[4];
    __shared__ int cnt_s;
    const int c = blockIdx.x, b = blockIdx.y;
    const unsigned long long* gk = wskeys + (size_t)b * NCAND;
    for (int i = threadIdx.x; i < NCAND; i += 256) sk[i] = gk[i];
    __syncthreads();

    const float* off0 = out + OFF_LCOFF + b * 2 * HW;
    const float* off1 = off0 + HW;
    const float* leng = out + OFF_LLENG + b * HW;
    const float* ang  = out + OFF_ANGLE + b * HW;

    #pragma unroll
    for (int q = 0; q < CHUNK / 256; ++q) {
        int lslot = q * 256 + threadIdx.x;       // slot within own chunk
        int mslot = c * CHUNK + lslot;
        unsigned long long e = sk[mslot];
        if (e == 0ULL) continue;                 // empty slot
        int rank = lslot;                        // local rank in own chunk
        #pragma unroll
        for (int c2 = 0; c2 < NCHUNK; ++c2) {
            if (c2 == c) continue;
            const unsigned long long* A = sk + c2 * CHUNK;
            int lo = 0, hi = CHUNK;
            while (lo < hi) {
                int mid = (lo + hi) >> 1;
                if (A[mid] > e) lo = mid + 1; else hi = mid;
            }
            rank += lo;                          // count of keys > e in c2
        }
        if (rank < NLINES) {
            unsigned p = 0xFFFFFFFFu - (unsigned)(e & 0xFFFFFFFFull);
            float score = __uint_as_float((unsigned)(e >> 32));
            int yi = (int)(p >> 7), xi = (int)(p & (WIDTH - 1));
            float yc = (float)yi + off0[p] + 0.5f;
            float xc = (float)xi + off1[p] + 0.5f;
            float hl = leng[p] * 64.0f;          // RESOLUTION/2
            float th = ang[p] * PI_F;
            float dy = hl * sinf(th);
            float dx = hl * cosf(th);
            float4 ln = make_float4(yc - dy, xc - dx, yc + dy, xc + dx);
            *(float4*)(out + OFF_LINES + (size_t)(b * NLINES + rank) * 4) = ln;
            out[OFF_SCORE + b * NLINES + rank] = score;
        }
    }

    // Fallback (never triggers for this data), chunk-0 block only:
    // pad ranks [cnt, 1000) with the lowest non-kept flat indices, score 0.
    // Rank ranges are disjoint from real candidates -> race-free vs other blocks.
    if (c != 0) return;
    int local = 0;
    for (int i = threadIdx.x; i < NCAND; i += 256) local += (sk[i] != 0ULL);
    for (int off = 32; off; off >>= 1) local += __shfl_down(local, off);
    if ((threadIdx.x & 63) == 0) wsum[threadIdx.x >> 6] = local;
    __syncthreads();
    if (threadIdx.x == 0) cnt_s = wsum[0] + wsum[1] + wsum[2] + wsum[3];
    __syncthreads();
    const int cnt = cnt_s;
    if (cnt < NLINES && threadIdx.x == 0) {
        const float* L = out + OFF_LCMAP + b * HW;
        int rank = cnt;
        for (int p = 0; p < HW && rank < NLINES; ++p) {
            if (keep_at(L, p)) continue;
            int yi = p >> 7, xi = p & (WIDTH - 1);
            float yc = (float)yi + off0[p] + 0.5f;
            float xc = (float)xi + off1[p] + 0.5f;
            float hl = leng[p] * 64.0f;
            float th = ang[p] * PI_F;
            float dy = hl * sinf(th);
            float dx = hl * cosf(th);
            float* lo = out + OFF_LINES + (size_t)(b * NLINES + rank) * 4;
            lo[0] = yc - dy; lo[1] = xc - dx; lo[2] = yc + dy; lo[3] = xc + dx;
            out[OFF_SCORE + b * NLINES + rank] = 0.0f;
            ++rank;
        }
    }
}

// K4: structure NMS. Grid (64 k-tiles, 32 batches), block 256 =
// 16 k x 16 i-splits of 63 -> max 63 iters/lane, 2048 blocks load-balance.
// __f*_rn intrinsics forbid fma contraction so dist matches reference rounding.
__global__ __launch_bounds__(256) void nms_kernel(float* __restrict__ out) {
    __shared__ float4 lsv[NLINES];               // 16 KB
    __shared__ unsigned char flags[NMS_KTILE][NMS_NSPLIT];
    const int tile = blockIdx.x, b = blockIdx.y;
    const float4* lg = (const float4*)(out + OFF_LINES + (size_t)b * NLINES * 4);
    for (int i = threadIdx.x; i < NLINES; i += 256) lsv[i] = lg[i];
    __syncthreads();

    const int kl = threadIdx.x & (NMS_KTILE - 1);
    const int s  = threadIdx.x >> 4;             // i-range split 0..15
    const int k  = tile * NMS_KTILE + kl;
    float4 P = lsv[k < NLINES ? k : 0];

    int istart = s * NMS_SPLIT;
    int iend = min(NMS_SPLIT * (s + 1), min(k, NLINES));
    bool sup = false;
    for (int i = istart; i < iend; ++i) {
        float4 Q = lsv[i];
        float a1 = __fadd_rn(__fmul_rn(Q.x - P.x, Q.x - P.x),
                             __fmul_rn(Q.y - P.y, Q.y - P.y));
        float a2 = __fadd_rn(__fmul_rn(Q.z - P.z, Q.z - P.z),
                             __fmul_rn(Q.w - P.w, Q.w - P.w));
        float d1 = __fadd_rn(a1, a2);
        float b1 = __fadd_rn(__fmul_rn(Q.x - P.z, Q.x - P.z),
                             __fmul_rn(Q.y - P.w, Q.y - P.w));
        float b2 = __fadd_rn(__fmul_rn(Q.z - P.x, Q.z - P.x),
                             __fmul_rn(Q.w - P.y, Q.w - P.y));
        float d2 = __fadd_rn(b1, b2);
        sup |= (fminf(d1, d2) <= 2.0f);
    }
    flags[kl][s] = (unsigned char)sup;
    __syncthreads();

    if (s == 0 && k < NLINES) {
        int any = 0;
        #pragma unroll
        for (int i = 0; i < NMS_NSPLIT; ++i) any |= flags[kl][i];
        float sc = out[OFF_SCORE + b * NLINES + k];
        out[OFF_SCORE + b * NLINES + k] = any ? 0.0f : sc;
    }
}

extern "C" void kernel_launch(void* const* d_in, const int* in_sizes, int n_in,
                              void* d_out, int out_size, void* d_ws, size_t ws_size,
                              hipStream_t stream) {
    const float* in = (const float*)d_in[0];
    float* out = (float*)d_out;
    (void)in_sizes; (void)n_in; (void)out_size;

    if (d_ws == nullptr || ws_size < WS_NEEDED) return;
    unsigned long long* wskeys = (unsigned long long*)d_ws;

    prep_collect_kernel<<<BATCH * 64, 256, 0, stream>>>(in, out, wskeys);
    sort_chunks_kernel<<<dim3(NCHUNK, BATCH), 512, 0, stream>>>(wskeys);
    merge_lines_kernel<<<dim3(NCHUNK, BATCH), 256, 0, stream>>>(out, wskeys);
    nms_kernel<<<dim3(64, BATCH), 256, 0, stream>>>(out);
}